// Round 10
// baseline (514.379 us; speedup 1.0000x reference)
//
#include <hip/hip_runtime.h>
#include <hip/hip_bf16.h>

// Problem constants
#define EDIM 1024
#define HHEADS 16
#define DHEAD 64
#define BB 4
#define NSEQ 4096
#define NTOK 16384   // BB*NSEQ
#define KVSPLIT 16

typedef unsigned short u16;
using frag8 = __attribute__((ext_vector_type(8))) short;   // 8 bf16 (4 VGPRs)
using facc4 = __attribute__((ext_vector_type(4))) float;   // 4 f32 acc

__device__ __forceinline__ float b2f(u16 u) {
  union { unsigned int i; float f; } c; c.i = ((unsigned int)u) << 16; return c.f;
}
__device__ __forceinline__ u16 f2b(float f) {
  __hip_bfloat16 h = __float2bfloat16(f);   // RNE
  union { __hip_bfloat16 h; u16 u; } c; c.h = h; return c.u;
}
__device__ __forceinline__ void gl2lds16(const void* g, void* l) {
  __builtin_amdgcn_global_load_lds(
      (const __attribute__((address_space(1))) unsigned int*)g,
      (__attribute__((address_space(3))) unsigned int*)l, 16, 0, 0);
}
__device__ __forceinline__ ushort4 cvt4(float4 a) {
  ushort4 r;
  r.x = f2b(a.x); r.y = f2b(a.y); r.z = f2b(a.z); r.w = f2b(a.w);
  return r;
}

// ---------------------------------------------------------------------------
// Dtype probe: flag[0]=1 -> inputs are bf16, 0 -> f32 (per reference).
// ---------------------------------------------------------------------------
__global__ void detect_dtype(const u16* __restrict__ src, unsigned* __restrict__ flag) {
  const int lane = threadIdx.x;                    // 64 threads
  const unsigned u = src[(size_t)lane * 200000];   // even u16 indices
  const unsigned e = (u >> 7) & 0xFF;
  const bool inl = (u == 0) || (e >= 100 && e <= 135);
  const unsigned long long m = __ballot(inl);
  if (lane == 0) flag[0] = (__popcll(m) >= 32) ? 1u : 0u;
}

// ---------------------------------------------------------------------------
// R9 cvt3: all 3 input embeddings in ONE launch, instruction-dense addressing.
// R8's cvt body interleaved 16B-of-32B loads / 8B-of-16B stores -> every
// memory instruction touched half a cache line -> 2.37 TB/s (38% of stream
// ceiling). Halves scheme: thread t owns float4-granule t and t + G/2, so
// each load/store instruction is fully dense across the wave.
// V-embed stages into d_out (dead until the final GEMM overwrites it).
// ---------------------------------------------------------------------------
#define G4 (NTOK * EDIM / 4)   // float4 granules per input = 4194304
struct Cvt3Args { const void* s[3]; u16* d[3]; };
__global__ __launch_bounds__(256) void cvt3(Cvt3Args a, const unsigned* __restrict__ flag) {
  if (flag[0] == 1) return;   // bf16 world: GEMM reads raw inputs directly
  const int t = blockIdx.x * 256 + threadIdx.x;    // 0 .. G4/2-1
  const float4* s = (const float4*)a.s[blockIdx.y];
  ushort4* d = (ushort4*)a.d[blockIdx.y];
  const float4 x = s[t];
  const float4 y = s[t + G4 / 2];
  d[t] = cvt4(x);
  d[t + G4 / 2] = cvt4(y);
}

// Merged weight/vector conversion: blocks [0,2048) convert the 4 weight
// matrices (512 blocks each, dense halves addressing); blocks [2048,2052)
// convert the 8 small vectors. One launch.
struct Ptr8 { const void* s[8]; u16* d[8]; };
struct WcvtArgs { const void* ws[4]; u16* wd[4]; Ptr8 p8; };
#define WG4 (EDIM * EDIM / 4)   // 262144 granules per weight
__global__ __launch_bounds__(256) void wcvt_all(WcvtArgs a, const unsigned* __restrict__ flag) {
  const int blk = blockIdx.x;
  if (blk < 2048) {
    if (flag[0] == 1) return;
    const int v = blk >> 9;
    const int t = (blk & 511) * 256 + threadIdx.x;   // 0 .. WG4/2-1
    const float4* s = (const float4*)a.ws[v];
    ushort4* d = (ushort4*)a.wd[v];
    d[t] = cvt4(s[t]);
    d[t + WG4 / 2] = cvt4(s[t + WG4 / 2]);
  } else {
    const int t = (blk - 2048) * 256 + threadIdx.x;   // 0..1023
    const int v = t >> 7;
    const int i0 = (t & 127) * 8;
    const void* s = a.p8.s[v];
    u16* d = a.p8.d[v];
    ushort4 lo, hi;
    if (flag[0] == 0) {
      lo = cvt4(((const float4*)s)[i0 >> 2]);
      hi = cvt4(((const float4*)s)[(i0 >> 2) + 1]);
    } else {
      lo = ((const ushort4*)s)[i0 >> 2];
      hi = ((const ushort4*)s)[(i0 >> 2) + 1];
    }
    ((ushort4*)d)[i0 >> 2] = lo;
    ((ushort4*)d)[(i0 >> 2) + 1] = hi;
  }
}

// ---------------------------------------------------------------------------
// GEMM: identical to R7/R8 (harness-verified). 256x256 tile, BK=64, 8 waves,
// 4-phase counted-vmcnt schedule with A-per-phase + B-reg-cached reads.
// ---------------------------------------------------------------------------
#define STA(BUF, QM, T)                                                       \
  gl2lds16(Ag + (size_t)(QM) * 64 * EDIM + (size_t)(T) * 64,                  \
           AsW + (BUF) * 16384 + (QM) * 8192);                                \
  gl2lds16(Ag + (size_t)(QM) * 64 * EDIM + 128 * EDIM + (size_t)(T) * 64,     \
           AsW + (BUF) * 16384 + (QM) * 8192 + 4096);

#define STB(BUF, QN, T)                                                       \
  gl2lds16(Bg + (size_t)(QN) * 32 * EDIM + (size_t)(T) * 64,                  \
           BsW + (BUF) * 16384 + (QN) * 8192);                                \
  gl2lds16(Bg + (size_t)(QN) * 32 * EDIM + 128 * EDIM + (size_t)(T) * 64,     \
           BsW + (BUF) * 16384 + (QN) * 8192 + 4096);

#define VM(N) asm volatile("s_waitcnt vmcnt(" #N ")" ::: "memory");

#define PH4(BUF, QM, LOADB, ISSUE, TAIL)                                      \
  {                                                                           \
    _Pragma("unroll") for (int i = 0; i < 4; ++i) {                           \
      const u16* rp = &As[BUF][QM][wm * 64 + i * 16 + fr][0];                 \
      af[i][0] = *(const frag8*)(rp + c0);                                    \
      af[i][1] = *(const frag8*)(rp + c1);                                    \
    }                                                                         \
    if (LOADB) {                                                              \
      _Pragma("unroll") for (int j = 0; j < 4; ++j) {                         \
        const u16* rp = &Bs[BUF][j >> 1][wn * 32 + (j & 1) * 16 + fr][0];     \
        bq[j][0] = *(const frag8*)(rp + c0);                                  \
        bq[j][1] = *(const frag8*)(rp + c1);                                  \
      }                                                                       \
    }                                                                         \
    ISSUE                                                                     \
    __builtin_amdgcn_s_barrier();                                             \
    asm volatile("s_waitcnt lgkmcnt(0)" ::: "memory");                        \
    __builtin_amdgcn_sched_barrier(0);                                        \
    __builtin_amdgcn_s_setprio(1);                                            \
    _Pragma("unroll") for (int kk = 0; kk < 2; ++kk)                          \
      _Pragma("unroll") for (int i = 0; i < 4; ++i)                           \
        _Pragma("unroll") for (int j = 0; j < 4; ++j)                         \
          acc[(QM) * 4 + i][j] =                                              \
              __builtin_amdgcn_mfma_f32_16x16x32_bf16(                        \
                  af[i][kk], bq[j][kk], acc[(QM) * 4 + i][j], 0, 0, 0);       \
    __builtin_amdgcn_s_setprio(0);                                            \
    TAIL                                                                      \
    __builtin_amdgcn_s_barrier();                                             \
    __builtin_amdgcn_sched_barrier(0);                                        \
  }

__global__ __launch_bounds__(512, 2) void gemm256(
    const void* __restrict__ Araw, const u16* __restrict__ Acvt,
    const void* __restrict__ Wraw, const u16* __restrict__ Wcvt,
    const u16* __restrict__ bias, u16* __restrict__ C,
    const unsigned* __restrict__ flag, int outMode)
{
  __shared__ __align__(16) u16 As[2][2][128][64];   // 64 KiB
  __shared__ __align__(16) u16 Bs[2][2][128][64];   // 64 KiB

  const int tid  = threadIdx.x;
  const int lane = tid & 63;
  const int w    = tid >> 6;       // 0..7
  const int wm   = w >> 2;         // 0..1 (M half)
  const int wn   = w & 3;          // 0..3 (N quarter)

  const int bid0 = blockIdx.x;
  const int bid  = (bid0 & 7) * 32 + (bid0 >> 3);
  const int rowBase = (bid >> 2) * 256;
  const int colBase = (bid & 3) * 256;

  const bool bfw = (flag[0] == 1);
  const u16* A  = bfw ? (const u16*)Araw : Acvt;
  const u16* Wt = bfw ? (const u16*)Wraw : Wcvt;

  const int lr = w * 8 + (lane >> 3);               // row within 64-row op
  const int sc = 8 * ((lane & 7) ^ (lane >> 3));    // swizzled col (elems)
  const u16* Ag = A  + (size_t)(rowBase + lr) * EDIM + sc;
  const u16* Bg = Wt + (size_t)(colBase + (lr >> 5) * 64 + (lr & 31)) * EDIM + sc;
  u16* AsW = &As[0][0][w * 8][0];   // + buf*16384 + region*8192 + o*4096
  u16* BsW = &Bs[0][0][w * 8][0];

  const int fr = lane & 15;
  const int qd = lane >> 4;
  const int sw = fr & 7;
  const int c0 = 8 * (qd ^ sw);          // kk=0 swizzled col offset (elems)
  const int c1 = 8 * ((qd + 4) ^ sw);    // kk=1

  facc4 acc[8][4];
#pragma unroll
  for (int i = 0; i < 8; ++i)
#pragma unroll
    for (int j = 0; j < 4; ++j) acc[i][j] = (facc4){0.f, 0.f, 0.f, 0.f};

  frag8 af[4][2];
  frag8 bq[4][2];

  STA(0, 0, 0) STB(0, 0, 0) STA(0, 1, 0) STB(0, 1, 0)
  STA(1, 0, 1) STB(1, 0, 1)
  VM(4)
  __builtin_amdgcn_s_barrier();
  __builtin_amdgcn_sched_barrier(0);

#pragma unroll 1
  for (int it = 0; it < 7; ++it) {                  // tiles 0..13
    const int t1 = 2 * it + 1, t2 = t1 + 1, t3 = t1 + 2;
    PH4(0, 0, 1, STA(1, 1, t1) STB(1, 1, t1), )
    PH4(0, 1, 0, STA(0, 0, t2) STB(0, 0, t2), VM(4))
    PH4(1, 0, 1, STA(0, 1, t2) STB(0, 1, t2), )
    PH4(1, 1, 0, STA(1, 0, t3) STB(1, 0, t3), VM(4))
  }
  PH4(0, 0, 1, STA(1, 1, 15) STB(1, 1, 15), )
  PH4(0, 1, 0, , VM(0))
  PH4(1, 0, 1, , )
  PH4(1, 1, 0, , )

  const bool f32out = (outMode == 1) && !bfw;
  float* Cf = (float*)C;
  float bvv[4];
#pragma unroll
  for (int j = 0; j < 4; ++j)
    bvv[j] = b2f(bias[colBase + wn * 64 + j * 16 + fr]);
#pragma unroll
  for (int i = 0; i < 8; ++i) {
#pragma unroll
    for (int r = 0; r < 4; ++r) {
      const int row = rowBase + wm * 128 + i * 16 + qd * 4 + r;
      const size_t ro = (size_t)row * EDIM + colBase + wn * 64 + fr;
#pragma unroll
      for (int j = 0; j < 4; ++j) {
        const float val = acc[i][j][r] + bvv[j];
        if (f32out) Cf[ro + j * 16] = val;
        else        C[ro + j * 16]  = f2b(val);
      }
    }
  }
}

// ---------------------------------------------------------------------------
// LayerNorm+elu+1: both tensors in one launch; one wave per row (16
// elems/lane), pure-shuffle reduction — no LDS, no __syncthreads.
// ---------------------------------------------------------------------------
struct LnArgs {
  const u16* X0; const u16* g0; const u16* b0; u16* Y0;
  const u16* X1; const u16* g1; const u16* b1; u16* Y1;
};
__global__ __launch_bounds__(256) void ln_elu2(LnArgs a) {
  const int tid = threadIdx.x, wv = tid >> 6, lane = tid & 63;
  const int rowg = blockIdx.x * 4 + wv;            // 0..32767
  const int sel = rowg >= NTOK;                    // wave-uniform
  const int row = sel ? rowg - NTOK : rowg;
  const u16* X = sel ? a.X1 : a.X0;
  const u16* g = sel ? a.g1 : a.g0;
  const u16* be = sel ? a.b1 : a.b0;
  u16* Y = sel ? a.Y1 : a.Y0;

  const uint4* xr = (const uint4*)(X + (size_t)row * EDIM);
  const uint4 v0 = xr[lane * 2];
  const uint4 v1 = xr[lane * 2 + 1];
  float xv[16];
  const u16* p0 = (const u16*)&v0;
  const u16* p1 = (const u16*)&v1;
#pragma unroll
  for (int j = 0; j < 8; ++j) { xv[j] = b2f(p0[j]); xv[8 + j] = b2f(p1[j]); }
  float s = 0.f, ss = 0.f;
#pragma unroll
  for (int j = 0; j < 16; ++j) { s += xv[j]; ss += xv[j] * xv[j]; }
#pragma unroll
  for (int off = 1; off < 64; off <<= 1) {
    s  += __shfl_xor(s,  off, 64);
    ss += __shfl_xor(ss, off, 64);
  }
  const float mu  = s * (1.0f / EDIM);
  const float var = ss * (1.0f / EDIM) - mu * mu;
  const float rs  = rsqrtf(var + 1e-5f);

  const uint4 gu0 = ((const uint4*)g)[lane * 2];
  const uint4 gu1 = ((const uint4*)g)[lane * 2 + 1];
  const uint4 bu0 = ((const uint4*)be)[lane * 2];
  const uint4 bu1 = ((const uint4*)be)[lane * 2 + 1];
  const u16* pg0 = (const u16*)&gu0; const u16* pg1 = (const u16*)&gu1;
  const u16* pb0 = (const u16*)&bu0; const u16* pb1 = (const u16*)&bu1;
  u16 o[16];
#pragma unroll
  for (int j = 0; j < 16; ++j) {
    const float gg = b2f(j < 8 ? pg0[j] : pg1[j - 8]);
    const float bb = b2f(j < 8 ? pb0[j] : pb1[j - 8]);
    float y = (xv[j] - mu) * rs * gg + bb;
    y = (y > 0.f) ? (y + 1.f) : __expf(y);   // elu(y)+1
    o[j] = f2b(y);
  }
  uint4* yr = (uint4*)(Y + (size_t)row * EDIM);
  yr[lane * 2]     = *(const uint4*)&o[0];
  yr[lane * 2 + 1] = *(const uint4*)&o[8];
}

// ---------------------------------------------------------------------------
// Stage 1: per-(split,h,b) partial kv_sum (64x64 f32) + partial k_sum -> own
// global slots (NO atomics). 256 n per block, 2 chunks of 128.  (unchanged)
// ---------------------------------------------------------------------------
__global__ __launch_bounds__(256) void kv_partial(
    const u16* __restrict__ Km, const u16* __restrict__ V,
    float* __restrict__ partials, float* __restrict__ kspart)
{
  __shared__ __align__(16) u16 smem[2 * 64 * 130];   // kT | vT, 33.3 KB
  u16 (*kT)[130] = (u16(*)[130])smem;
  u16 (*vT)[130] = (u16(*)[130])(smem + 64 * 130);
  float* red = (float*)smem;            // pitch 68; reused after MFMA (<=17.4KB)
  float* ksr = ((float*)smem) + 4352;   // 4 waves x 64 floats

  const int split = blockIdx.x, h = blockIdx.y, b = blockIdx.z;
  const int bh = b * HHEADS + h;
  const int tid = threadIdx.x, lane = tid & 63, w = tid >> 6;
  const size_t base = (size_t)b * NSEQ * EDIM + h * DHEAD;
  const int nbase = split * (NSEQ / KVSPLIT);   // 256 n per block

  float ksacc[8] = {0, 0, 0, 0, 0, 0, 0, 0};
  facc4 acc[4][4];
#pragma unroll
  for (int i = 0; i < 4; ++i)
#pragma unroll
    for (int j = 0; j < 4; ++j) acc[i][j] = (facc4){0.f, 0.f, 0.f, 0.f};

  const int e0 = (tid & 7) * 8;
  const int nl0 = tid >> 3;      // 0..31
  const int fr = lane & 15;
  const int quad = lane >> 4;

  for (int c = 0; c < 2; ++c) {
    const int nchunk = nbase + c * 128;
#pragma unroll
    for (int rep = 0; rep < 4; ++rep) {
      const int n = rep * 32 + nl0;
      const uint4 kd = *(const uint4*)(Km + base + (size_t)(nchunk + n) * EDIM + e0);
      const uint4 vd = *(const uint4*)(V  + base + (size_t)(nchunk + n) * EDIM + e0);
      const u16* pk = (const u16*)&kd;
      const u16* pv = (const u16*)&vd;
#pragma unroll
      for (int ii = 0; ii < 8; ++ii) {
        kT[e0 + ii][n] = pk[ii];
        ksacc[ii] += b2f(pk[ii]);
        vT[e0 + ii][n] = pv[ii];
      }
    }
    __syncthreads();
    const int kq2 = w * 32 + quad * 8;   // wave w contracts n in [w*32,(w+1)*32)
    frag8 af[4], bf[4];
#pragma unroll
    for (int i = 0; i < 4; ++i) af[i] = *(const frag8*)&kT[i * 16 + fr][kq2];
#pragma unroll
    for (int j = 0; j < 4; ++j) bf[j] = *(const frag8*)&vT[j * 16 + fr][kq2];
#pragma unroll
    for (int i = 0; i < 4; ++i)
#pragma unroll
      for (int j = 0; j < 4; ++j)
        acc[i][j] = __builtin_amdgcn_mfma_f32_16x16x32_bf16(af[i], bf[j], acc[i][j], 0, 0, 0);
    __syncthreads();
  }

  // rotated cross-wave reduction into red (pitch 68)
  for (int p = 0; p < 4; ++p) {
    const int j = (w + p) & 3;
#pragma unroll
    for (int i = 0; i < 4; ++i)
#pragma unroll
      for (int r = 0; r < 4; ++r) {
        const int d = i * 16 + quad * 4 + r;
        const int e = j * 16 + fr;
        if (p == 0) red[d * 68 + e] = acc[i][j][r];
        else        red[d * 68 + e] += acc[i][j][r];
      }
    __syncthreads();
  }

  // write 64x64 partial (coalesced)
  const size_t pbase = ((size_t)bh * KVSPLIT + split) * 4096;
#pragma unroll
  for (int ii = 0; ii < 16; ++ii) {
    const int idx = tid + ii * 256;
    partials[pbase + idx] = red[(idx >> 6) * 68 + (idx & 63)];
  }

  // k_sum partial: shuffle-tree over stride-8 lane groups, then cross-wave LDS
#pragma unroll
  for (int ii = 0; ii < 8; ++ii) {
    ksacc[ii] += __shfl_down(ksacc[ii], 32, 64);
    ksacc[ii] += __shfl_down(ksacc[ii], 16, 64);
    ksacc[ii] += __shfl_down(ksacc[ii], 8, 64);
  }
  if (lane < 8) {
#pragma unroll
    for (int ii = 0; ii < 8; ++ii) ksr[w * 64 + lane * 8 + ii] = ksacc[ii];
  }
  __syncthreads();
  if (tid < 64)
    kspart[((size_t)bh * KVSPLIT + split) * 64 + tid] =
        ksr[tid] + ksr[64 + tid] + ksr[128 + tid] + ksr[192 + tid];
}

// Stage 2: reduce KVSPLIT partial slots -> KV bf16 [d][e] and Ks f32.
__global__ __launch_bounds__(256) void kv_reduce(
    const float* __restrict__ partials, const float* __restrict__ kspart,
    u16* __restrict__ KVb, float* __restrict__ Ks)
{
  const int qt = blockIdx.x;   // 0..3
  const int bh = blockIdx.y;   // 0..63
  const int tid = threadIdx.x;
#pragma unroll
  for (int ii = 0; ii < 4; ++ii) {
    const int idx = qt * 1024 + ii * 256 + tid;
    float s = 0.f;
#pragma unroll
    for (int sp = 0; sp < KVSPLIT; ++sp)
      s += partials[((size_t)bh * KVSPLIT + sp) * 4096 + idx];
    KVb[(size_t)bh * 4096 + idx] = f2b(s);
  }
  if (qt == 0 && tid < 64) {
    float s = 0.f;
#pragma unroll
    for (int sp = 0; sp < KVSPLIT; ++sp)
      s += kspart[((size_t)bh * KVSPLIT + sp) * 64 + tid];
    Ks[bh * 64 + tid] = s;
  }
}

// ---------------------------------------------------------------------------
// attn[b,q,h,e] = (sum_d q[b,q,h,d]*kv[bh][d][e]) / (q . ksum[bh] + 1e-8)
// KV arrives pre-converted bf16.
// ---------------------------------------------------------------------------
__global__ __launch_bounds__(256) void attn_nd(
    const u16* __restrict__ Q, const u16* __restrict__ KVb,
    const float* __restrict__ Ks, u16* __restrict__ O)
{
  __shared__ __align__(16) u16 kvT[64][72];  // [e][d], pad +8
  __shared__ float ks_s[64];
  __shared__ float den_s[4][16];
  const int qt = blockIdx.x, h = blockIdx.y, b = blockIdx.z;
  const int bh = b * HHEADS + h;
  const int tid = threadIdx.x, lane = tid & 63, w = tid >> 6;
  const u16* kvp = KVb + (size_t)bh * 4096;
#pragma unroll
  for (int ii = 0; ii < 16; ++ii) {
    const int idx = tid + ii * 256;          // idx = d*64+e
    kvT[idx & 63][idx >> 6] = kvp[idx];
  }
  if (tid < 64) ks_s[tid] = Ks[bh * 64 + tid];
  __syncthreads();

  const int fr = lane & 15;
  const int q8 = (lane >> 4) * 8;
  const u16* qp = Q + (size_t)(b * NSEQ + qt * 64 + w * 16 + fr) * EDIM + h * DHEAD;
  const frag8 a0 = *(const frag8*)(qp + q8);
  const frag8 a1 = *(const frag8*)(qp + 32 + q8);

  const u16* a0u = (const u16*)&a0;
  const u16* a1u = (const u16*)&a1;
  float den = 0.f;
#pragma unroll
  for (int j = 0; j < 8; ++j)
    den += b2f(a0u[j]) * ks_s[q8 + j] + b2f(a1u[j]) * ks_s[32 + q8 + j];
  den += __shfl_xor(den, 16, 64);
  den += __shfl_xor(den, 32, 64);
  if (lane < 16) den_s[w][lane] = den + 1e-8f;

  facc4 acc[4];
#pragma unroll
  for (int j = 0; j < 4; ++j) acc[j] = (facc4){0.f, 0.f, 0.f, 0.f};
#pragma unroll
  for (int j = 0; j < 4; ++j) {
    const frag8 b0 = *(const frag8*)&kvT[j * 16 + fr][q8];
    const frag8 b1 = *(const frag8*)&kvT[j * 16 + fr][32 + q8];
    acc[j] = __builtin_amdgcn_mfma_f32_16x16x32_bf16(a0, b0, acc[j], 0, 0, 0);
    acc[j] = __builtin_amdgcn_mfma_f32_16x16x32_bf16(a1, b1, acc[j], 0, 0, 0);
  }
  __syncthreads();
#pragma unroll
  for (int r = 0; r < 4; ++r) {
    const int rq = (lane >> 4) * 4 + r;
    const float dv = den_s[w][rq];
    const size_t orow = (size_t)(b * NSEQ + qt * 64 + w * 16 + rq) * EDIM + h * DHEAD;
#pragma unroll
    for (int j = 0; j < 4; ++j)
      O[orow + j * 16 + fr] = f2b(acc[j][r] / dv);
  }
}

// ---------------------------------------------------------------------------
extern "C" void kernel_launch(void* const* d_in, const int* in_sizes, int n_in,
                              void* d_out, int out_size, void* d_ws, size_t ws_size,
                              hipStream_t stream) {
  char* ws = (char*)d_ws;
  const size_t EH = (size_t)NTOK * EDIM;      // 16.78M elems
  unsigned* flag = (unsigned*)ws;             // 1 KB slot
  u16* Wqb  = (u16*)(ws + 1024);
  u16* Wkb  = Wqb + EDIM * EDIM;
  u16* Wvb  = Wkb + EDIM * EDIM;
  u16* Wob  = Wvb + EDIM * EDIM;
  u16* bqb  = Wob + EDIM * EDIM;
  u16* bkb  = bqb + 1024;
  u16* bvb  = bkb + 1024;
  u16* bob  = bvb + 1024;
  u16* gqb  = bob + 1024;
  u16* bEqb = gqb + 1024;
  u16* gkb  = bEqb + 1024;
  u16* bEkb = gkb + 1024;
  u16* Xin  = bEkb + 1024;    // staging A (query); later attn output
  u16* preQ = Xin + EH;
  u16* preK = preQ + EH;
  u16* vbuf = preK + EH;      // staging B (key embed), then V matrix
  float* partials = (float*)(vbuf + EH);              // 64*16*4096 f32 = 16MB
  float* kspart   = partials + (size_t)64 * KVSPLIT * 4096;  // 64*16*64 f32
  float* kvbuf    = kspart + (size_t)64 * KVSPLIT * 64;      // 64*4096 slot
  float* ksbuf    = kvbuf + (size_t)64 * 4096;               // 64*64 f32
  u16* kvbf = (u16*)kvbuf;    // bf16 KV lives in the old f32 slot
  u16* vstg = (u16*)d_out;    // value-embed staging aliases d_out (dead
                              // until the final GEMM overwrites it)

  const dim3 gg(256), tb(512);

  detect_dtype<<<1, 64, 0, stream>>>((const u16*)d_in[0], flag);

  WcvtArgs wa;
  wa.ws[0] = d_in[3]; wa.ws[1] = d_in[5]; wa.ws[2] = d_in[7]; wa.ws[3] = d_in[9];
  wa.wd[0] = Wqb;     wa.wd[1] = Wkb;     wa.wd[2] = Wvb;     wa.wd[3] = Wob;
  wa.p8.s[0] = d_in[4];  wa.p8.s[1] = d_in[6];  wa.p8.s[2] = d_in[8];  wa.p8.s[3] = d_in[10];
  wa.p8.s[4] = d_in[11]; wa.p8.s[5] = d_in[12]; wa.p8.s[6] = d_in[13]; wa.p8.s[7] = d_in[14];
  wa.p8.d[0] = bqb; wa.p8.d[1] = bkb; wa.p8.d[2] = bvb; wa.p8.d[3] = bob;
  wa.p8.d[4] = gqb; wa.p8.d[5] = bEqb; wa.p8.d[6] = gkb; wa.p8.d[7] = bEkb;
  wcvt_all<<<2052, 256, 0, stream>>>(wa, flag);

  Cvt3Args ca;
  ca.s[0] = d_in[0]; ca.d[0] = Xin;
  ca.s[1] = d_in[1]; ca.d[1] = vbuf;
  ca.s[2] = d_in[2]; ca.d[2] = vstg;
  cvt3<<<dim3(G4 / 512, 3), 256, 0, stream>>>(ca, flag);

  gemm256<<<gg, tb, 0, stream>>>(d_in[0], Xin,  d_in[3], Wqb, bqb, preQ, flag, 0);
  gemm256<<<gg, tb, 0, stream>>>(d_in[1], vbuf, d_in[5], Wkb, bkb, preK, flag, 0);
  gemm256<<<gg, tb, 0, stream>>>(d_in[2], vstg, d_in[7], Wvb, bvb, vbuf, flag, 0);

  LnArgs la;
  la.X0 = preQ; la.g0 = gqb; la.b0 = bEqb; la.Y0 = preQ;
  la.X1 = preK; la.g1 = gkb; la.b1 = bEkb; la.Y1 = preK;
  ln_elu2<<<8192, 256, 0, stream>>>(la);

  kv_partial<<<dim3(KVSPLIT, HHEADS, BB), dim3(256), 0, stream>>>(preK, vbuf, partials, kspart);
  kv_reduce<<<dim3(4, 64), dim3(256), 0, stream>>>(partials, kspart, kvbf, ksbuf);
  attn_nd<<<dim3(NSEQ / 64, HHEADS, BB), dim3(256), 0, stream>>>(preQ, kvbf, ksbuf, Xin);
  gemm256<<<gg, tb, 0, stream>>>(Xin, Xin, d_in[9], Wob, bob, (u16*)d_out, flag, 1);
}

// Round 11
// 513.714 us; speedup vs baseline: 1.0013x; 1.0013x over previous
//
#include <hip/hip_runtime.h>
#include <hip/hip_bf16.h>

// Problem constants
#define EDIM 1024
#define HHEADS 16
#define DHEAD 64
#define BB 4
#define NSEQ 4096
#define NTOK 16384   // BB*NSEQ
#define KVSPLIT 16

typedef unsigned short u16;
using frag8 = __attribute__((ext_vector_type(8))) short;   // 8 bf16 (4 VGPRs)
using facc4 = __attribute__((ext_vector_type(4))) float;   // 4 f32 acc

__device__ __forceinline__ float b2f(u16 u) {
  union { unsigned int i; float f; } c; c.i = ((unsigned int)u) << 16; return c.f;
}
__device__ __forceinline__ u16 f2b(float f) {
  __hip_bfloat16 h = __float2bfloat16(f);   // RNE
  union { __hip_bfloat16 h; u16 u; } c; c.h = h; return c.u;
}
__device__ __forceinline__ void gl2lds16(const void* g, void* l) {
  __builtin_amdgcn_global_load_lds(
      (const __attribute__((address_space(1))) unsigned int*)g,
      (__attribute__((address_space(3))) unsigned int*)l, 16, 0, 0);
}
__device__ __forceinline__ ushort4 cvt4(float4 a) {
  ushort4 r;
  r.x = f2b(a.x); r.y = f2b(a.y); r.z = f2b(a.z); r.w = f2b(a.w);
  return r;
}

// ---------------------------------------------------------------------------
// Dtype probe: flag[0]=1 -> inputs are bf16, 0 -> f32 (per reference).
// ---------------------------------------------------------------------------
__global__ void detect_dtype(const u16* __restrict__ src, unsigned* __restrict__ flag) {
  const int lane = threadIdx.x;                    // 64 threads
  const unsigned u = src[(size_t)lane * 200000];   // even u16 indices
  const unsigned e = (u >> 7) & 0xFF;
  const bool inl = (u == 0) || (e >= 100 && e <= 135);
  const unsigned long long m = __ballot(inl);
  if (lane == 0) flag[0] = (__popcll(m) >= 32) ? 1u : 0u;
}

// ---------------------------------------------------------------------------
// R11 cvt3: MLP-batched. R10 counters (Little's law): 22 waves/CU resident,
// wave lifetime ~11.5K cyc for 2 loads -> only 44KB/CU outstanding -> 2.4
// TB/s. kv_partial (8 loads/wave in flight) hits 5.3 TB/s on the same mixed
// stream. Fix: each thread loads 16 independent float4 (256B) back-to-back
// (16 in flight per wave), then converts+stores; 1024 blocks per tensor
// (grid-stride spirit of Guideline 11) instead of 8192.
// Coverage: granule = blk*4096 + i*256 + tid, blk in [0,1024) -> bijective
// over G4 per tensor. Every load/store instruction dense across the wave.
// V-embed stages into d_out (dead until the final GEMM overwrites it).
// ---------------------------------------------------------------------------
#define G4 (NTOK * EDIM / 4)   // float4 granules per input = 4194304
#define CVT_PT 16              // granules per thread
struct Cvt3Args { const void* s[3]; u16* d[3]; };
__global__ __launch_bounds__(256) void cvt3(Cvt3Args a, const unsigned* __restrict__ flag) {
  if (flag[0] == 1) return;   // bf16 world: GEMM reads raw inputs directly
  const int base = blockIdx.x * (256 * CVT_PT) + threadIdx.x;
  const float4* s = (const float4*)a.s[blockIdx.y];
  ushort4* d = (ushort4*)a.d[blockIdx.y];
  float4 v[CVT_PT];
#pragma unroll
  for (int i = 0; i < CVT_PT; ++i) v[i] = s[base + i * 256];
#pragma unroll
  for (int i = 0; i < CVT_PT; ++i) d[base + i * 256] = cvt4(v[i]);
}

// Merged weight/vector conversion: blocks [0,2048) convert the 4 weight
// matrices (512 blocks each, dense halves addressing); blocks [2048,2052)
// convert the 8 small vectors. One launch.  (unchanged from R9/R10)
struct Ptr8 { const void* s[8]; u16* d[8]; };
struct WcvtArgs { const void* ws[4]; u16* wd[4]; Ptr8 p8; };
#define WG4 (EDIM * EDIM / 4)   // 262144 granules per weight
__global__ __launch_bounds__(256) void wcvt_all(WcvtArgs a, const unsigned* __restrict__ flag) {
  const int blk = blockIdx.x;
  if (blk < 2048) {
    if (flag[0] == 1) return;
    const int v = blk >> 9;
    const int t = (blk & 511) * 256 + threadIdx.x;   // 0 .. WG4/2-1
    const float4* s = (const float4*)a.ws[v];
    ushort4* d = (ushort4*)a.wd[v];
    d[t] = cvt4(s[t]);
    d[t + WG4 / 2] = cvt4(s[t + WG4 / 2]);
  } else {
    const int t = (blk - 2048) * 256 + threadIdx.x;   // 0..1023
    const int v = t >> 7;
    const int i0 = (t & 127) * 8;
    const void* s = a.p8.s[v];
    u16* d = a.p8.d[v];
    ushort4 lo, hi;
    if (flag[0] == 0) {
      lo = cvt4(((const float4*)s)[i0 >> 2]);
      hi = cvt4(((const float4*)s)[(i0 >> 2) + 1]);
    } else {
      lo = ((const ushort4*)s)[i0 >> 2];
      hi = ((const ushort4*)s)[(i0 >> 2) + 1];
    }
    ((ushort4*)d)[i0 >> 2] = lo;
    ((ushort4*)d)[(i0 >> 2) + 1] = hi;
  }
}

// ---------------------------------------------------------------------------
// GEMM: identical to R7/R8 (harness-verified). 256x256 tile, BK=64, 8 waves,
// 4-phase counted-vmcnt schedule with A-per-phase + B-reg-cached reads.
// ---------------------------------------------------------------------------
#define STA(BUF, QM, T)                                                       \
  gl2lds16(Ag + (size_t)(QM) * 64 * EDIM + (size_t)(T) * 64,                  \
           AsW + (BUF) * 16384 + (QM) * 8192);                                \
  gl2lds16(Ag + (size_t)(QM) * 64 * EDIM + 128 * EDIM + (size_t)(T) * 64,     \
           AsW + (BUF) * 16384 + (QM) * 8192 + 4096);

#define STB(BUF, QN, T)                                                       \
  gl2lds16(Bg + (size_t)(QN) * 32 * EDIM + (size_t)(T) * 64,                  \
           BsW + (BUF) * 16384 + (QN) * 8192);                                \
  gl2lds16(Bg + (size_t)(QN) * 32 * EDIM + 128 * EDIM + (size_t)(T) * 64,     \
           BsW + (BUF) * 16384 + (QN) * 8192 + 4096);

#define VM(N) asm volatile("s_waitcnt vmcnt(" #N ")" ::: "memory");

#define PH4(BUF, QM, LOADB, ISSUE, TAIL)                                      \
  {                                                                           \
    _Pragma("unroll") for (int i = 0; i < 4; ++i) {                           \
      const u16* rp = &As[BUF][QM][wm * 64 + i * 16 + fr][0];                 \
      af[i][0] = *(const frag8*)(rp + c0);                                    \
      af[i][1] = *(const frag8*)(rp + c1);                                    \
    }                                                                         \
    if (LOADB) {                                                              \
      _Pragma("unroll") for (int j = 0; j < 4; ++j) {                         \
        const u16* rp = &Bs[BUF][j >> 1][wn * 32 + (j & 1) * 16 + fr][0];     \
        bq[j][0] = *(const frag8*)(rp + c0);                                  \
        bq[j][1] = *(const frag8*)(rp + c1);                                  \
      }                                                                       \
    }                                                                         \
    ISSUE                                                                     \
    __builtin_amdgcn_s_barrier();                                             \
    asm volatile("s_waitcnt lgkmcnt(0)" ::: "memory");                        \
    __builtin_amdgcn_sched_barrier(0);                                        \
    __builtin_amdgcn_s_setprio(1);                                            \
    _Pragma("unroll") for (int kk = 0; kk < 2; ++kk)                          \
      _Pragma("unroll") for (int i = 0; i < 4; ++i)                           \
        _Pragma("unroll") for (int j = 0; j < 4; ++j)                         \
          acc[(QM) * 4 + i][j] =                                              \
              __builtin_amdgcn_mfma_f32_16x16x32_bf16(                        \
                  af[i][kk], bq[j][kk], acc[(QM) * 4 + i][j], 0, 0, 0);       \
    __builtin_amdgcn_s_setprio(0);                                            \
    TAIL                                                                      \
    __builtin_amdgcn_s_barrier();                                             \
    __builtin_amdgcn_sched_barrier(0);                                        \
  }

__global__ __launch_bounds__(512, 2) void gemm256(
    const void* __restrict__ Araw, const u16* __restrict__ Acvt,
    const void* __restrict__ Wraw, const u16* __restrict__ Wcvt,
    const u16* __restrict__ bias, u16* __restrict__ C,
    const unsigned* __restrict__ flag, int outMode)
{
  __shared__ __align__(16) u16 As[2][2][128][64];   // 64 KiB
  __shared__ __align__(16) u16 Bs[2][2][128][64];   // 64 KiB

  const int tid  = threadIdx.x;
  const int lane = tid & 63;
  const int w    = tid >> 6;       // 0..7
  const int wm   = w >> 2;         // 0..1 (M half)
  const int wn   = w & 3;          // 0..3 (N quarter)

  const int bid0 = blockIdx.x;
  const int bid  = (bid0 & 7) * 32 + (bid0 >> 3);
  const int rowBase = (bid >> 2) * 256;
  const int colBase = (bid & 3) * 256;

  const bool bfw = (flag[0] == 1);
  const u16* A  = bfw ? (const u16*)Araw : Acvt;
  const u16* Wt = bfw ? (const u16*)Wraw : Wcvt;

  const int lr = w * 8 + (lane >> 3);               // row within 64-row op
  const int sc = 8 * ((lane & 7) ^ (lane >> 3));    // swizzled col (elems)
  const u16* Ag = A  + (size_t)(rowBase + lr) * EDIM + sc;
  const u16* Bg = Wt + (size_t)(colBase + (lr >> 5) * 64 + (lr & 31)) * EDIM + sc;
  u16* AsW = &As[0][0][w * 8][0];   // + buf*16384 + region*8192 + o*4096
  u16* BsW = &Bs[0][0][w * 8][0];

  const int fr = lane & 15;
  const int qd = lane >> 4;
  const int sw = fr & 7;
  const int c0 = 8 * (qd ^ sw);          // kk=0 swizzled col offset (elems)
  const int c1 = 8 * ((qd + 4) ^ sw);    // kk=1

  facc4 acc[8][4];
#pragma unroll
  for (int i = 0; i < 8; ++i)
#pragma unroll
    for (int j = 0; j < 4; ++j) acc[i][j] = (facc4){0.f, 0.f, 0.f, 0.f};

  frag8 af[4][2];
  frag8 bq[4][2];

  STA(0, 0, 0) STB(0, 0, 0) STA(0, 1, 0) STB(0, 1, 0)
  STA(1, 0, 1) STB(1, 0, 1)
  VM(4)
  __builtin_amdgcn_s_barrier();
  __builtin_amdgcn_sched_barrier(0);

#pragma unroll 1
  for (int it = 0; it < 7; ++it) {                  // tiles 0..13
    const int t1 = 2 * it + 1, t2 = t1 + 1, t3 = t1 + 2;
    PH4(0, 0, 1, STA(1, 1, t1) STB(1, 1, t1), )
    PH4(0, 1, 0, STA(0, 0, t2) STB(0, 0, t2), VM(4))
    PH4(1, 0, 1, STA(0, 1, t2) STB(0, 1, t2), )
    PH4(1, 1, 0, STA(1, 0, t3) STB(1, 0, t3), VM(4))
  }
  PH4(0, 0, 1, STA(1, 1, 15) STB(1, 1, 15), )
  PH4(0, 1, 0, , VM(0))
  PH4(1, 0, 1, , )
  PH4(1, 1, 0, , )

  const bool f32out = (outMode == 1) && !bfw;
  float* Cf = (float*)C;
  float bvv[4];
#pragma unroll
  for (int j = 0; j < 4; ++j)
    bvv[j] = b2f(bias[colBase + wn * 64 + j * 16 + fr]);
#pragma unroll
  for (int i = 0; i < 8; ++i) {
#pragma unroll
    for (int r = 0; r < 4; ++r) {
      const int row = rowBase + wm * 128 + i * 16 + qd * 4 + r;
      const size_t ro = (size_t)row * EDIM + colBase + wn * 64 + fr;
#pragma unroll
      for (int j = 0; j < 4; ++j) {
        const float val = acc[i][j][r] + bvv[j];
        if (f32out) Cf[ro + j * 16] = val;
        else        C[ro + j * 16]  = f2b(val);
      }
    }
  }
}

// ---------------------------------------------------------------------------
// LayerNorm+elu+1: both tensors in one launch; one wave per row (16
// elems/lane), pure-shuffle reduction — no LDS, no __syncthreads.
// ---------------------------------------------------------------------------
struct LnArgs {
  const u16* X0; const u16* g0; const u16* b0; u16* Y0;
  const u16* X1; const u16* g1; const u16* b1; u16* Y1;
};
__global__ __launch_bounds__(256) void ln_elu2(LnArgs a) {
  const int tid = threadIdx.x, wv = tid >> 6, lane = tid & 63;
  const int rowg = blockIdx.x * 4 + wv;            // 0..32767
  const int sel = rowg >= NTOK;                    // wave-uniform
  const int row = sel ? rowg - NTOK : rowg;
  const u16* X = sel ? a.X1 : a.X0;
  const u16* g = sel ? a.g1 : a.g0;
  const u16* be = sel ? a.b1 : a.b0;
  u16* Y = sel ? a.Y1 : a.Y0;

  const uint4* xr = (const uint4*)(X + (size_t)row * EDIM);
  const uint4 v0 = xr[lane * 2];
  const uint4 v1 = xr[lane * 2 + 1];
  float xv[16];
  const u16* p0 = (const u16*)&v0;
  const u16* p1 = (const u16*)&v1;
#pragma unroll
  for (int j = 0; j < 8; ++j) { xv[j] = b2f(p0[j]); xv[8 + j] = b2f(p1[j]); }
  float s = 0.f, ss = 0.f;
#pragma unroll
  for (int j = 0; j < 16; ++j) { s += xv[j]; ss += xv[j] * xv[j]; }
#pragma unroll
  for (int off = 1; off < 64; off <<= 1) {
    s  += __shfl_xor(s,  off, 64);
    ss += __shfl_xor(ss, off, 64);
  }
  const float mu  = s * (1.0f / EDIM);
  const float var = ss * (1.0f / EDIM) - mu * mu;
  const float rs  = rsqrtf(var + 1e-5f);

  const uint4 gu0 = ((const uint4*)g)[lane * 2];
  const uint4 gu1 = ((const uint4*)g)[lane * 2 + 1];
  const uint4 bu0 = ((const uint4*)be)[lane * 2];
  const uint4 bu1 = ((const uint4*)be)[lane * 2 + 1];
  const u16* pg0 = (const u16*)&gu0; const u16* pg1 = (const u16*)&gu1;
  const u16* pb0 = (const u16*)&bu0; const u16* pb1 = (const u16*)&bu1;
  u16 o[16];
#pragma unroll
  for (int j = 0; j < 16; ++j) {
    const float gg = b2f(j < 8 ? pg0[j] : pg1[j - 8]);
    const float bb = b2f(j < 8 ? pb0[j] : pb1[j - 8]);
    float y = (xv[j] - mu) * rs * gg + bb;
    y = (y > 0.f) ? (y + 1.f) : __expf(y);   // elu(y)+1
    o[j] = f2b(y);
  }
  uint4* yr = (uint4*)(Y + (size_t)row * EDIM);
  yr[lane * 2]     = *(const uint4*)&o[0];
  yr[lane * 2 + 1] = *(const uint4*)&o[8];
}

// ---------------------------------------------------------------------------
// Stage 1: per-(split,h,b) partial kv_sum (64x64 f32) + partial k_sum -> own
// global slots (NO atomics). 256 n per block, 2 chunks of 128.  (unchanged)
// ---------------------------------------------------------------------------
__global__ __launch_bounds__(256) void kv_partial(
    const u16* __restrict__ Km, const u16* __restrict__ V,
    float* __restrict__ partials, float* __restrict__ kspart)
{
  __shared__ __align__(16) u16 smem[2 * 64 * 130];   // kT | vT, 33.3 KB
  u16 (*kT)[130] = (u16(*)[130])smem;
  u16 (*vT)[130] = (u16(*)[130])(smem + 64 * 130);
  float* red = (float*)smem;            // pitch 68; reused after MFMA (<=17.4KB)
  float* ksr = ((float*)smem) + 4352;   // 4 waves x 64 floats

  const int split = blockIdx.x, h = blockIdx.y, b = blockIdx.z;
  const int bh = b * HHEADS + h;
  const int tid = threadIdx.x, lane = tid & 63, w = tid >> 6;
  const size_t base = (size_t)b * NSEQ * EDIM + h * DHEAD;
  const int nbase = split * (NSEQ / KVSPLIT);   // 256 n per block

  float ksacc[8] = {0, 0, 0, 0, 0, 0, 0, 0};
  facc4 acc[4][4];
#pragma unroll
  for (int i = 0; i < 4; ++i)
#pragma unroll
    for (int j = 0; j < 4; ++j) acc[i][j] = (facc4){0.f, 0.f, 0.f, 0.f};

  const int e0 = (tid & 7) * 8;
  const int nl0 = tid >> 3;      // 0..31
  const int fr = lane & 15;
  const int quad = lane >> 4;

  for (int c = 0; c < 2; ++c) {
    const int nchunk = nbase + c * 128;
#pragma unroll
    for (int rep = 0; rep < 4; ++rep) {
      const int n = rep * 32 + nl0;
      const uint4 kd = *(const uint4*)(Km + base + (size_t)(nchunk + n) * EDIM + e0);
      const uint4 vd = *(const uint4*)(V  + base + (size_t)(nchunk + n) * EDIM + e0);
      const u16* pk = (const u16*)&kd;
      const u16* pv = (const u16*)&vd;
#pragma unroll
      for (int ii = 0; ii < 8; ++ii) {
        kT[e0 + ii][n] = pk[ii];
        ksacc[ii] += b2f(pk[ii]);
        vT[e0 + ii][n] = pv[ii];
      }
    }
    __syncthreads();
    const int kq2 = w * 32 + quad * 8;   // wave w contracts n in [w*32,(w+1)*32)
    frag8 af[4], bf[4];
#pragma unroll
    for (int i = 0; i < 4; ++i) af[i] = *(const frag8*)&kT[i * 16 + fr][kq2];
#pragma unroll
    for (int j = 0; j < 4; ++j) bf[j] = *(const frag8*)&vT[j * 16 + fr][kq2];
#pragma unroll
    for (int i = 0; i < 4; ++i)
#pragma unroll
      for (int j = 0; j < 4; ++j)
        acc[i][j] = __builtin_amdgcn_mfma_f32_16x16x32_bf16(af[i], bf[j], acc[i][j], 0, 0, 0);
    __syncthreads();
  }

  // rotated cross-wave reduction into red (pitch 68)
  for (int p = 0; p < 4; ++p) {
    const int j = (w + p) & 3;
#pragma unroll
    for (int i = 0; i < 4; ++i)
#pragma unroll
      for (int r = 0; r < 4; ++r) {
        const int d = i * 16 + quad * 4 + r;
        const int e = j * 16 + fr;
        if (p == 0) red[d * 68 + e] = acc[i][j][r];
        else        red[d * 68 + e] += acc[i][j][r];
      }
    __syncthreads();
  }

  // write 64x64 partial (coalesced)
  const size_t pbase = ((size_t)bh * KVSPLIT + split) * 4096;
#pragma unroll
  for (int ii = 0; ii < 16; ++ii) {
    const int idx = tid + ii * 256;
    partials[pbase + idx] = red[(idx >> 6) * 68 + (idx & 63)];
  }

  // k_sum partial: shuffle-tree over stride-8 lane groups, then cross-wave LDS
#pragma unroll
  for (int ii = 0; ii < 8; ++ii) {
    ksacc[ii] += __shfl_down(ksacc[ii], 32, 64);
    ksacc[ii] += __shfl_down(ksacc[ii], 16, 64);
    ksacc[ii] += __shfl_down(ksacc[ii], 8, 64);
  }
  if (lane < 8) {
#pragma unroll
    for (int ii = 0; ii < 8; ++ii) ksr[w * 64 + lane * 8 + ii] = ksacc[ii];
  }
  __syncthreads();
  if (tid < 64)
    kspart[((size_t)bh * KVSPLIT + split) * 64 + tid] =
        ksr[tid] + ksr[64 + tid] + ksr[128 + tid] + ksr[192 + tid];
}

// Stage 2: reduce KVSPLIT partial slots -> KV bf16 [d][e] and Ks f32.
__global__ __launch_bounds__(256) void kv_reduce(
    const float* __restrict__ partials, const float* __restrict__ kspart,
    u16* __restrict__ KVb, float* __restrict__ Ks)
{
  const int qt = blockIdx.x;   // 0..3
  const int bh = blockIdx.y;   // 0..63
  const int tid = threadIdx.x;
#pragma unroll
  for (int ii = 0; ii < 4; ++ii) {
    const int idx = qt * 1024 + ii * 256 + tid;
    float s = 0.f;
#pragma unroll
    for (int sp = 0; sp < KVSPLIT; ++sp)
      s += partials[((size_t)bh * KVSPLIT + sp) * 4096 + idx];
    KVb[(size_t)bh * 4096 + idx] = f2b(s);
  }
  if (qt == 0 && tid < 64) {
    float s = 0.f;
#pragma unroll
    for (int sp = 0; sp < KVSPLIT; ++sp)
      s += kspart[((size_t)bh * KVSPLIT + sp) * 64 + tid];
    Ks[bh * 64 + tid] = s;
  }
}

// ---------------------------------------------------------------------------
// attn[b,q,h,e] = (sum_d q[b,q,h,d]*kv[bh][d][e]) / (q . ksum[bh] + 1e-8)
// KV arrives pre-converted bf16.
// ---------------------------------------------------------------------------
__global__ __launch_bounds__(256) void attn_nd(
    const u16* __restrict__ Q, const u16* __restrict__ KVb,
    const float* __restrict__ Ks, u16* __restrict__ O)
{
  __shared__ __align__(16) u16 kvT[64][72];  // [e][d], pad +8
  __shared__ float ks_s[64];
  __shared__ float den_s[4][16];
  const int qt = blockIdx.x, h = blockIdx.y, b = blockIdx.z;
  const int bh = b * HHEADS + h;
  const int tid = threadIdx.x, lane = tid & 63, w = tid >> 6;
  const u16* kvp = KVb + (size_t)bh * 4096;
#pragma unroll
  for (int ii = 0; ii < 16; ++ii) {
    const int idx = tid + ii * 256;          // idx = d*64+e
    kvT[idx & 63][idx >> 6] = kvp[idx];
  }
  if (tid < 64) ks_s[tid] = Ks[bh * 64 + tid];
  __syncthreads();

  const int fr = lane & 15;
  const int q8 = (lane >> 4) * 8;
  const u16* qp = Q + (size_t)(b * NSEQ + qt * 64 + w * 16 + fr) * EDIM + h * DHEAD;
  const frag8 a0 = *(const frag8*)(qp + q8);
  const frag8 a1 = *(const frag8*)(qp + 32 + q8);

  const u16* a0u = (const u16*)&a0;
  const u16* a1u = (const u16*)&a1;
  float den = 0.f;
#pragma unroll
  for (int j = 0; j < 8; ++j)
    den += b2f(a0u[j]) * ks_s[q8 + j] + b2f(a1u[j]) * ks_s[32 + q8 + j];
  den += __shfl_xor(den, 16, 64);
  den += __shfl_xor(den, 32, 64);
  if (lane < 16) den_s[w][lane] = den + 1e-8f;

  facc4 acc[4];
#pragma unroll
  for (int j = 0; j < 4; ++j) acc[j] = (facc4){0.f, 0.f, 0.f, 0.f};
#pragma unroll
  for (int j = 0; j < 4; ++j) {
    const frag8 b0 = *(const frag8*)&kvT[j * 16 + fr][q8];
    const frag8 b1 = *(const frag8*)&kvT[j * 16 + fr][32 + q8];
    acc[j] = __builtin_amdgcn_mfma_f32_16x16x32_bf16(a0, b0, acc[j], 0, 0, 0);
    acc[j] = __builtin_amdgcn_mfma_f32_16x16x32_bf16(a1, b1, acc[j], 0, 0, 0);
  }
  __syncthreads();
#pragma unroll
  for (int r = 0; r < 4; ++r) {
    const int rq = (lane >> 4) * 4 + r;
    const float dv = den_s[w][rq];
    const size_t orow = (size_t)(b * NSEQ + qt * 64 + w * 16 + rq) * EDIM + h * DHEAD;
#pragma unroll
    for (int j = 0; j < 4; ++j)
      O[orow + j * 16 + fr] = f2b(acc[j][r] / dv);
  }
}

// ---------------------------------------------------------------------------
extern "C" void kernel_launch(void* const* d_in, const int* in_sizes, int n_in,
                              void* d_out, int out_size, void* d_ws, size_t ws_size,
                              hipStream_t stream) {
  char* ws = (char*)d_ws;
  const size_t EH = (size_t)NTOK * EDIM;      // 16.78M elems
  unsigned* flag = (unsigned*)ws;             // 1 KB slot
  u16* Wqb  = (u16*)(ws + 1024);
  u16* Wkb  = Wqb + EDIM * EDIM;
  u16* Wvb  = Wkb + EDIM * EDIM;
  u16* Wob  = Wvb + EDIM * EDIM;
  u16* bqb  = Wob + EDIM * EDIM;
  u16* bkb  = bqb + 1024;
  u16* bvb  = bkb + 1024;
  u16* bob  = bvb + 1024;
  u16* gqb  = bob + 1024;
  u16* bEqb = gqb + 1024;
  u16* gkb  = bEqb + 1024;
  u16* bEkb = gkb + 1024;
  u16* Xin  = bEkb + 1024;    // staging A (query); later attn output
  u16* preQ = Xin + EH;
  u16* preK = preQ + EH;
  u16* vbuf = preK + EH;      // staging B (key embed), then V matrix
  float* partials = (float*)(vbuf + EH);              // 64*16*4096 f32 = 16MB
  float* kspart   = partials + (size_t)64 * KVSPLIT * 4096;  // 64*16*64 f32
  float* kvbuf    = kspart + (size_t)64 * KVSPLIT * 64;      // 64*4096 slot
  float* ksbuf    = kvbuf + (size_t)64 * 4096;               // 64*64 f32
  u16* kvbf = (u16*)kvbuf;    // bf16 KV lives in the old f32 slot
  u16* vstg = (u16*)d_out;    // value-embed staging aliases d_out (dead
                              // until the final GEMM overwrites it)

  const dim3 gg(256), tb(512);

  detect_dtype<<<1, 64, 0, stream>>>((const u16*)d_in[0], flag);

  WcvtArgs wa;
  wa.ws[0] = d_in[3]; wa.ws[1] = d_in[5]; wa.ws[2] = d_in[7]; wa.ws[3] = d_in[9];
  wa.wd[0] = Wqb;     wa.wd[1] = Wkb;     wa.wd[2] = Wvb;     wa.wd[3] = Wob;
  wa.p8.s[0] = d_in[4];  wa.p8.s[1] = d_in[6];  wa.p8.s[2] = d_in[8];  wa.p8.s[3] = d_in[10];
  wa.p8.s[4] = d_in[11]; wa.p8.s[5] = d_in[12]; wa.p8.s[6] = d_in[13]; wa.p8.s[7] = d_in[14];
  wa.p8.d[0] = bqb; wa.p8.d[1] = bkb; wa.p8.d[2] = bvb; wa.p8.d[3] = bob;
  wa.p8.d[4] = gqb; wa.p8.d[5] = bEqb; wa.p8.d[6] = gkb; wa.p8.d[7] = bEkb;
  wcvt_all<<<2052, 256, 0, stream>>>(wa, flag);

  Cvt3Args ca;
  ca.s[0] = d_in[0]; ca.d[0] = Xin;
  ca.s[1] = d_in[1]; ca.d[1] = vbuf;
  ca.s[2] = d_in[2]; ca.d[2] = vstg;
  cvt3<<<dim3(G4 / (256 * CVT_PT), 3), 256, 0, stream>>>(ca, flag);

  gemm256<<<gg, tb, 0, stream>>>(d_in[0], Xin,  d_in[3], Wqb, bqb, preQ, flag, 0);
  gemm256<<<gg, tb, 0, stream>>>(d_in[1], vbuf, d_in[5], Wkb, bkb, preK, flag, 0);
  gemm256<<<gg, tb, 0, stream>>>(d_in[2], vstg, d_in[7], Wvb, bvb, vbuf, flag, 0);

  LnArgs la;
  la.X0 = preQ; la.g0 = gqb; la.b0 = bEqb; la.Y0 = preQ;
  la.X1 = preK; la.g1 = gkb; la.b1 = bEkb; la.Y1 = preK;
  ln_elu2<<<8192, 256, 0, stream>>>(la);

  kv_partial<<<dim3(KVSPLIT, HHEADS, BB), dim3(256), 0, stream>>>(preK, vbuf, partials, kspart);
  kv_reduce<<<dim3(4, 64), dim3(256), 0, stream>>>(partials, kspart, kvbf, ksbuf);
  attn_nd<<<dim3(NSEQ / 64, HHEADS, BB), dim3(256), 0, stream>>>(preQ, kvbf, ksbuf, Xin);
  gemm256<<<gg, tb, 0, stream>>>(Xin, Xin, d_in[9], Wob, bob, (u16*)d_out, flag, 1);
}